// Round 9
// baseline (232.733 us; speedup 1.0000x reference)
//
#include <hip/hip_runtime.h>

// YOLO layer: (64, 3*85, 44, 44) -> (64, 3*44*44, 85), fp32.
// R3-R6: four structures all 79-87 us (~2.4 TB/s), all pipes idle; ruled out:
// bank conflicts (R4), barriers (R5), NT stores (R6), request count (R5's 64B
// granules cost only +6%). Shared defect of the fast variants: drain-to-zero
// convoy -- outstanding load bytes/CU collapse every ~2K cycles, each block
// restarts cold. R5 tested pipelining but confounded it with 64B granules.
// R7 = clean experiment: persistent 6-tile blocks, prefetch depth 3 (12 KB/
// wave continuously in flight), 256B granules, packed LDS, normal stores.
// Loads are UNPREDICATED (clamped addresses) so the compiler emits counted
// vmcnt(N) instead of conservative drains. ~96 VGPR -> 16 waves/CU (accepted:
// trade occupancy for steady-state streaming).
// R7/R8 resubmits: GPU acquisition timeouts, no data.

#define BSZ      64
#define NA       3
#define NC       80
#define GRID     44
#define SPATIAL  (GRID * GRID)        // 1936
#define CH       (5 + NC)             // 85
#define TILE     64
#define TPB      31                   // tiles per (b,a) slab
#define NTL      (BSZ * NA * TPB)     // 5952 tiles
#define NT       6                    // tiles per block
#define NBLK     (NTL / NT)           // 992
#define NXCD     8
#define CHUNKB   (NBLK / NXCD)        // 124 (992 % 8 == 0: bijective)
#define NF       (CH * (TILE / 4))    // 1360 float4 loads per tile
#define STRIDE_F 8.0f                 // 352/44; cancels /STRIDE in scaled anchors

typedef float vfloat4 __attribute__((ext_vector_type(4)));

__device__ __forceinline__ float sigf(float x) {
    return 1.0f / (1.0f + __expf(-x));
}

struct TileCtx { int s0, valid, ba; float aw, ah; };

__device__ __forceinline__ TileCtx tctx(int T) {
    TileCtx tc;
    int t    = T % TPB;               // magic-mul
    tc.ba    = T / TPB;
    tc.s0    = t * TILE;
    tc.valid = min(TILE, SPATIAL - tc.s0);   // 64, or 16 on last tile of slab
    int a = tc.ba % NA;
    tc.aw = (a == 0) ? 10.0f : (a == 1) ? 16.0f : 33.0f;
    tc.ah = (a == 0) ? 13.0f : (a == 1) ? 30.0f : 23.0f;
    return tc;
}

// Unpredicated float4 loads, clamped in-bounds: every wave issues exactly 6
// VMEM instrs -> compiler can count vmcnt precisely. 16 lanes/channel = 256B
// contiguous granule per channel row.
__device__ __forceinline__ void issue(const float* __restrict__ in,
                                      const TileCtx& tc, int tid,
                                      float4 (&v)[6]) {
    const float* ib = in + (size_t)tc.ba * CH * SPATIAL + tc.s0;
    #pragma unroll
    for (int i = 0; i < 6; ++i) {
        int f = tid + i * 256;        // f -> (channel c, spatial quad q)
        int c = min(f >> 4, CH - 1);  // clamp tail (f>=1360) to ch 84
        int off = min((f & 15) * 4, tc.valid - 4);   // clamp quads on 16-tail
        v[i] = *(const float4*)(ib + (size_t)c * SPATIAL + off);
    }
}

// Transform + transpose-write into packed [s][c] LDS (2-way max bank alias).
__device__ __forceinline__ void transform(const TileCtx& tc, int tid,
                                          const float4 (&v)[6],
                                          float* __restrict__ tile) {
    #pragma unroll
    for (int i = 0; i < 6; ++i) {
        int f = tid + i * 256;
        int c = f >> 4, q = f & 15;
        if (f >= NF || q * 4 >= tc.valid) continue;   // VALU-side only
        float r[4] = {v[i].x, v[i].y, v[i].z, v[i].w};
        #pragma unroll
        for (int j = 0; j < 4; ++j) {
            int   sl = q * 4 + j;
            int   gs = tc.s0 + sl;
            float x  = r[j];
            float o;
            if (c == 0)      o = (sigf(x) + (float)(gs % GRID)) * STRIDE_F;
            else if (c == 1) o = (sigf(x) + (float)(gs / GRID)) * STRIDE_F;
            else if (c == 2) o = __expf(x) * tc.aw;
            else if (c == 3) o = __expf(x) * tc.ah;
            else             o = sigf(x);             // conf + 80 classes
            tile[sl * CH + c] = o;
        }
    }
}

// Contiguous ds_read_b128 + float4 stores: LDS is the exact output image.
__device__ __forceinline__ void flush(float* __restrict__ out,
                                      const TileCtx& tc, int tid,
                                      const float* __restrict__ tile) {
    const size_t ob = ((size_t)tc.ba * SPATIAL + tc.s0) * (size_t)CH;
    const int total = tc.valid * CH;  // 5440 or 1360, mult of 4
    for (int k4 = tid * 4; k4 < total; k4 += 1024) {
        vfloat4 w = *(const vfloat4*)(tile + k4);
        *(vfloat4*)(out + ob + k4) = w;
    }
}

__global__ __launch_bounds__(256, 4)
void yolo_kernel(const float* __restrict__ in, float* __restrict__ out) {
    __shared__ float tile[TILE * CH];     // 21,760 B packed [s][c]

    const int bid0 = blockIdx.x;
    const int bid  = (bid0 % NXCD) * CHUNKB + bid0 / NXCD;   // XCD-chunked
    const int tid  = threadIdx.x;
    const int T0   = bid * NT;

    float4 v0[6], v1[6], v2[6];
    TileCtx t0 = tctx(T0);
    TileCtx t1 = tctx(T0 + 1);
    TileCtx t2;
    issue(in, t0, tid, v0);               // depth-3 pipeline prologue
    issue(in, t1, tid, v1);

    #pragma unroll
    for (int k = 0; k < NT; ++k) {
        if (k + 2 < NT) {                 // keep 2 tiles of loads in flight
            t2 = tctx(T0 + k + 2);
            issue(in, t2, tid, v2);
        }
        transform(t0, tid, v0, tile);     // counted vmcnt: waits v0 only
        __syncthreads();
        flush(out, t0, tid, tile);
        if (k + 1 < NT) __syncthreads();  // WAR: LDS reused next iter
        t0 = t1; t1 = t2;
        #pragma unroll
        for (int i = 0; i < 6; ++i) { v0[i] = v1[i]; v1[i] = v2[i]; }
    }
}

extern "C" void kernel_launch(void* const* d_in, const int* in_sizes, int n_in,
                              void* d_out, int out_size, void* d_ws, size_t ws_size,
                              hipStream_t stream) {
    const float* in = (const float*)d_in[0];
    float* out = (float*)d_out;
    yolo_kernel<<<NBLK, 256, 0, stream>>>(in, out);
}